// Round 3
// baseline (1942.900 us; speedup 1.0000x reference)
//
#include <hip/hip_runtime.h>
#include <hip/hip_fp16.h>

#define B_ 256
#define T_ 512
#define H_ 128
#define M_ (B_ * T_)  // 131072 rows

typedef _Float16 f16x8 __attribute__((ext_vector_type(8)));
typedef float    f32x4 __attribute__((ext_vector_type(4)));

__device__ __forceinline__ float sigmoid_f(float a) { return 1.f / (1.f + __expf(-a)); }
__device__ __forceinline__ float tanh_f(float a) { return 1.f - 2.f / (__expf(2.f * a) + 1.f); }

// ---------- one-time conversions ----------
__global__ __launch_bounds__(256)
void convert_kernel(const float* __restrict__ x,
                    const float* __restrict__ Wih0, const float* __restrict__ bih0, const float* __restrict__ bhh0,
                    const float* __restrict__ Whh0, const float* __restrict__ Whh1,
                    const float* __restrict__ Wih1, const float* __restrict__ bih1, const float* __restrict__ bhh1,
                    const float* __restrict__ Wl, const float* __restrict__ bl,
                    const float* __restrict__ Wo, const float* __restrict__ bo,
                    __half* __restrict__ x16, __half* __restrict__ W0h, __half* __restrict__ W1h,
                    __half* __restrict__ Whh0h, __half* __restrict__ Whh1h,
                    __half* __restrict__ Wc16, float* __restrict__ b0, float* __restrict__ b1,
                    float* __restrict__ bc)
{
    const int tid = threadIdx.x, bid = blockIdx.x;
    if (bid == 0) {
        for (int i = tid; i < 512; i += 256) { b0[i] = bih0[i] + bhh0[i]; b1[i] = bih1[i] + bhh1[i]; }
        for (int i = tid; i < 512 * 32; i += 256) {
            int r = i >> 5, k = i & 31;
            W0h[i] = __float2half(k < 30 ? Wih0[r * 30 + k] : 0.f);
        }
        for (int i = tid; i < 64 * 128; i += 256) {
            int j = i >> 7, k = i & 127;
            float a = 0.f;
            if (j < 63) for (int m = 0; m < 84; ++m) a += Wo[j * 84 + m] * Wl[m * 128 + k];
            Wc16[i] = __float2half(a);
        }
        if (tid < 64) {
            float a = 0.f;
            if (tid < 63) { a = bo[tid]; for (int m = 0; m < 84; ++m) a += Wo[tid * 84 + m] * bl[m]; }
            bc[tid] = a;
        }
    } else if (bid == 1) {
        for (int i = tid; i < 512 * 128; i += 256) W1h[i] = __float2half(Wih1[i]);
    } else if (bid == 2) {
        for (int i = tid; i < 512 * 128; i += 256) Whh0h[i] = __float2half(Whh0[i]);
    } else if (bid == 3) {
        for (int i = tid; i < 512 * 128; i += 256) Whh1h[i] = __float2half(Whh1[i]);
    } else {
        const int base = (bid - 4) * 256;  // row base
        const float* xs = x + (size_t)base * 30;
        for (int i = tid; i < 256 * 30; i += 256) {
            int r = i / 30, k = i - r * 30;
            x16[(size_t)(base + r) * 32 + k] = __float2half(xs[i]);
        }
        for (int i = tid; i < 512; i += 256) {
            int r = i >> 1, k = 30 + (i & 1);
            x16[(size_t)(base + r) * 32 + k] = __float2half(0.f);
        }
    }
}

// ---------- projection GEMM with gate-interleaved output: xp[m][4j+q] ----------
// wave wn owns unit-tiles {2wn, 2wn+1} x gates {0..3}; lane packs {i,f,g,o}(j) -> uint2
template<int KK>
__global__ __launch_bounds__(256, 4)
void proj512_kernel(const __half* __restrict__ in, const __half* __restrict__ W16,
                    const float* __restrict__ bias, __half* __restrict__ xp)
{
    constexpr int KT = KK / 32;
    const int lane = threadIdx.x & 63;
    const int wn = threadIdx.x >> 6;     // 0..3
    const int rowbase = blockIdx.x * 32; // ROWT=2
    const int l15 = lane & 15, qg = lane >> 4, lk = qg * 8;

    float bs[2][4];
#pragma unroll
    for (int jt = 0; jt < 2; ++jt)
#pragma unroll
        for (int q = 0; q < 4; ++q)
            bs[jt][q] = bias[q * 128 + (2 * wn + jt) * 16 + l15];

    f32x4 acc[2][4][2];  // [jt][q][rt]
#pragma unroll
    for (int jt = 0; jt < 2; ++jt)
#pragma unroll
        for (int q = 0; q < 4; ++q)
#pragma unroll
            for (int rt = 0; rt < 2; ++rt) acc[jt][q][rt] = (f32x4){0.f, 0.f, 0.f, 0.f};

#pragma unroll
    for (int kt = 0; kt < KT; ++kt) {
        f16x8 a[2];
#pragma unroll
        for (int rt = 0; rt < 2; ++rt)
            a[rt] = *reinterpret_cast<const f16x8*>(in + (size_t)(rowbase + rt * 16 + l15) * KK + kt * 32 + lk);
#pragma unroll
        for (int jt = 0; jt < 2; ++jt)
#pragma unroll
            for (int q = 0; q < 4; ++q) {
                f16x8 bv = *reinterpret_cast<const f16x8*>(
                    W16 + (size_t)(q * 128 + (2 * wn + jt) * 16 + l15) * KK + kt * 32 + lk);
#pragma unroll
                for (int rt = 0; rt < 2; ++rt)
                    acc[jt][q][rt] = __builtin_amdgcn_mfma_f32_16x16x32_f16(a[rt], bv, acc[jt][q][rt], 0, 0, 0);
            }
    }
#pragma unroll
    for (int jt = 0; jt < 2; ++jt) {
        const int jg = (2 * wn + jt) * 16 + l15;
#pragma unroll
        for (int rt = 0; rt < 2; ++rt)
#pragma unroll
            for (int r = 0; r < 4; ++r) {
                const int m = rowbase + rt * 16 + qg * 4 + r;
                __half2 lo = __floats2half2_rn(acc[jt][0][rt][r] + bs[jt][0], acc[jt][1][rt][r] + bs[jt][1]);
                __half2 hi = __floats2half2_rn(acc[jt][2][rt][r] + bs[jt][2], acc[jt][3][rt][r] + bs[jt][3]);
                uint2 pk;
                pk.x = __builtin_bit_cast(unsigned, lo);
                pk.y = __builtin_bit_cast(unsigned, hi);
                *reinterpret_cast<uint2*>(xp + (size_t)m * 512 + 4 * jg) = pk;
            }
    }
}

// ---------- recurrence via MFMA: 16 batches/block, gates lane-local ----------
__global__ __launch_bounds__(512, 2)
void lstm_rec_mfma(const __half* __restrict__ xp, const __half* __restrict__ Whh16,
                   __half* __restrict__ hout)
{
    const int bb = blockIdx.x;       // 0..15
    const int tid = threadIdx.x;
    const int w = tid >> 6;          // wave 0..7 -> units 16w..16w+15
    const int lane = tid & 63;
    const int l15 = lane & 15, qg = lane >> 4;
    const int j = w * 16 + l15;      // this lane's unit

    // B-fragments of Whh (gate q, unit j): 64 VGPRs, loaded once
    f16x8 wb[4][4];
#pragma unroll
    for (int q = 0; q < 4; ++q)
#pragma unroll
        for (int kt = 0; kt < 4; ++kt)
            wb[q][kt] = *reinterpret_cast<const f16x8*>(
                Whh16 + (size_t)(q * 128 + j) * 128 + kt * 32 + qg * 8);

    __shared__ __align__(16) __half hbuf[2][16 * 128];  // double-buffered, XOR-swizzled
    for (int i = tid; i < 2048; i += 512) hbuf[0][i] = __float2half(0.f);

    size_t xoff[4];
    __half* hp[4];
#pragma unroll
    for (int r = 0; r < 4; ++r) {
        int b = bb * 16 + qg * 4 + r;
        xoff[r] = (size_t)b * 512 * 512 + 4 * j;
        hp[r] = hout + (size_t)b * T_ * H_ + j;
    }
    uint2 xq[4];
#pragma unroll
    for (int r = 0; r < 4; ++r) xq[r] = *reinterpret_cast<const uint2*>(xp + xoff[r]);
    float c[4] = {0.f, 0.f, 0.f, 0.f};
    __syncthreads();

    char* rd = (char*)&hbuf[0][0];
    char* wr2 = (char*)&hbuf[1][0];
    for (int t = 0; t < T_; ++t) {
        // A-fragments: h rows, swizzled
        f16x8 a[4];
#pragma unroll
        for (int kt = 0; kt < 4; ++kt) {
            int byte = (l15 * 256 + kt * 64 + qg * 16) ^ ((l15 & 7) << 4);
            a[kt] = *reinterpret_cast<const f16x8*>(rd + byte);
        }
        // prefetch next xp
        uint2 xqn[4] = {xq[0], xq[1], xq[2], xq[3]};
        if (t + 1 < T_) {
#pragma unroll
            for (int r = 0; r < 4; ++r)
                xqn[r] = *reinterpret_cast<const uint2*>(xp + xoff[r] + (size_t)(t + 1) * 512);
        }
        // acc init = xp (bias folded): C-layout rows are batches, cols are this lane's unit
        f32x4 acc[4];
#pragma unroll
        for (int r = 0; r < 4; ++r) {
            float2 flo = __half22float2(__builtin_bit_cast(__half2, xq[r].x));
            float2 fhi = __half22float2(__builtin_bit_cast(__half2, xq[r].y));
            acc[0][r] = flo.x; acc[1][r] = flo.y; acc[2][r] = fhi.x; acc[3][r] = fhi.y;
        }
#pragma unroll
        for (int kt = 0; kt < 4; ++kt)
#pragma unroll
            for (int q = 0; q < 4; ++q)
                acc[q] = __builtin_amdgcn_mfma_f32_16x16x32_f16(a[kt], wb[q][kt], acc[q], 0, 0, 0);

        __half hh[4];
#pragma unroll
        for (int r = 0; r < 4; ++r) {
            float iv = sigmoid_f(acc[0][r]);
            float fv = sigmoid_f(acc[1][r]);
            float gv = tanh_f(acc[2][r]);
            float ov = sigmoid_f(acc[3][r]);
            c[r] = fv * c[r] + iv * gv;
            float h = ov * tanh_f(c[r]);
            hh[r] = __float2half(h);
        }
        // write h to next buffer (swizzled) + global
#pragma unroll
        for (int r = 0; r < 4; ++r) {
            int row = qg * 4 + r;
            int byte = (row * 256 + j * 2) ^ ((row & 7) << 4);
            *reinterpret_cast<__half*>(wr2 + byte) = hh[r];
            hp[r][(size_t)t * H_] = hh[r];
        }
        __syncthreads();
        char* tmp = rd; rd = wr2; wr2 = tmp;
#pragma unroll
        for (int r = 0; r < 4; ++r) xq[r] = xqn[r];
    }
}

// ---------- head: out = h2 @ Wc^T + bc (63 cols, f32) ----------
__global__ __launch_bounds__(256, 4)
void head_kernel(const __half* __restrict__ in, const __half* __restrict__ W16,
                 const float* __restrict__ bias, float* __restrict__ outp)
{
    constexpr int KK = 128;
    const int lane = threadIdx.x & 63;
    const int wn = threadIdx.x >> 6;
    const int rowbase = blockIdx.x * 64;  // ROWT=4
    const int colbase = wn * 16;
    const int l15 = lane & 15, lk = (lane >> 4) * 8;

    float bcol = bias[colbase + l15];
    f32x4 acc[4];
#pragma unroll
    for (int rt = 0; rt < 4; ++rt) acc[rt] = (f32x4){0.f, 0.f, 0.f, 0.f};

#pragma unroll
    for (int kt = 0; kt < 4; ++kt) {
        f16x8 bv = *reinterpret_cast<const f16x8*>(W16 + (size_t)(colbase + l15) * KK + kt * 32 + lk);
#pragma unroll
        for (int rt = 0; rt < 4; ++rt) {
            f16x8 a = *reinterpret_cast<const f16x8*>(in + (size_t)(rowbase + rt * 16 + l15) * KK + kt * 32 + lk);
            acc[rt] = __builtin_amdgcn_mfma_f32_16x16x32_f16(a, bv, acc[rt], 0, 0, 0);
        }
    }
    const int col = colbase + l15;
#pragma unroll
    for (int rt = 0; rt < 4; ++rt)
#pragma unroll
        for (int r = 0; r < 4; ++r) {
            const int row = rowbase + rt * 16 + (lane >> 4) * 4 + r;
            if (col < 63) outp[(size_t)row * 63 + col] = acc[rt][r] + bcol;
        }
}

extern "C" void kernel_launch(void* const* d_in, const int* in_sizes, int n_in,
                              void* d_out, int out_size, void* d_ws, size_t ws_size,
                              hipStream_t stream)
{
    const float* x    = (const float*)d_in[0];
    const float* Wih0 = (const float*)d_in[1];
    const float* Whh0 = (const float*)d_in[2];
    const float* bih0 = (const float*)d_in[3];
    const float* bhh0 = (const float*)d_in[4];
    const float* Wih1 = (const float*)d_in[5];
    const float* Whh1 = (const float*)d_in[6];
    const float* bih1 = (const float*)d_in[7];
    const float* bhh1 = (const float*)d_in[8];
    const float* Wl   = (const float*)d_in[9];
    const float* bl   = (const float*)d_in[10];
    const float* Wo   = (const float*)d_in[11];
    const float* bo   = (const float*)d_in[12];
    float* out = (float*)d_out;

    char* ws = (char*)d_ws;
    size_t off = 0;
    auto carve = [&](size_t bytes) { void* p = ws + off; off += (bytes + 255) & ~(size_t)255; return p; };
    __half* xp  = (__half*)carve((size_t)M_ * 512 * 2);  // 134 MB, shared by both layers
    __half* h1  = (__half*)carve((size_t)M_ * 128 * 2);  // 33.5 MB
    __half* h2  = (__half*)carve((size_t)M_ * 128 * 2);  // 33.5 MB
    __half* x16 = h2;                                    // alias: x16 dead before h2 written
    __half* W0h   = (__half*)carve(512 * 32 * 2);
    __half* W1h   = (__half*)carve(512 * 128 * 2);
    __half* Whh0h = (__half*)carve(512 * 128 * 2);
    __half* Whh1h = (__half*)carve(512 * 128 * 2);
    __half* Wc16  = (__half*)carve(64 * 128 * 2);
    float*  b0    = (float*)carve(512 * 4);
    float*  b1    = (float*)carve(512 * 4);
    float*  bc    = (float*)carve(64 * 4);

    hipLaunchKernelGGL(convert_kernel, dim3(4 + M_ / 256), dim3(256), 0, stream,
                       x, Wih0, bih0, bhh0, Whh0, Whh1, Wih1, bih1, bhh1, Wl, bl, Wo, bo,
                       x16, W0h, W1h, Whh0h, Whh1h, Wc16, b0, b1, bc);

    // layer 0
    hipLaunchKernelGGL((proj512_kernel<32>), dim3(M_ / 32), dim3(256), 0, stream,
                       x16, W0h, b0, xp);
    hipLaunchKernelGGL(lstm_rec_mfma, dim3(16), dim3(512), 0, stream, xp, Whh0h, h1);

    // layer 1
    hipLaunchKernelGGL((proj512_kernel<128>), dim3(M_ / 32), dim3(256), 0, stream,
                       h1, W1h, b1, xp);
    hipLaunchKernelGGL(lstm_rec_mfma, dim3(16), dim3(512), 0, stream, xp, Whh1h, h2);

    // head
    hipLaunchKernelGGL(head_kernel, dim3(M_ / 64), dim3(256), 0, stream,
                       h2, Wc16, bc, out);
}

// Round 4
// 909.274 us; speedup vs baseline: 2.1368x; 2.1368x over previous
//
#include <hip/hip_runtime.h>
#include <hip/hip_fp16.h>

#define B_ 256
#define T_ 512
#define H_ 128
#define M_ (B_ * T_)  // 131072 rows

typedef _Float16 f16x8 __attribute__((ext_vector_type(8)));
typedef float    f32x4 __attribute__((ext_vector_type(4)));

__device__ __forceinline__ float rcp_f(float a) { return __builtin_amdgcn_rcpf(a); }
__device__ __forceinline__ float sigmoid_f(float a) { return rcp_f(1.f + __expf(-a)); }
__device__ __forceinline__ float tanh_f(float a) { return 1.f - 2.f * rcp_f(__expf(2.f * a) + 1.f); }

// ---------- one-time conversions ----------
__global__ __launch_bounds__(256)
void convert_kernel(const float* __restrict__ x,
                    const float* __restrict__ Wih0, const float* __restrict__ bih0, const float* __restrict__ bhh0,
                    const float* __restrict__ Whh0, const float* __restrict__ Whh1,
                    const float* __restrict__ Wih1, const float* __restrict__ bih1, const float* __restrict__ bhh1,
                    const float* __restrict__ Wl, const float* __restrict__ bl,
                    const float* __restrict__ Wo, const float* __restrict__ bo,
                    __half* __restrict__ x16, __half* __restrict__ W0h, __half* __restrict__ W1h,
                    __half* __restrict__ Whh0h, __half* __restrict__ Whh1h,
                    __half* __restrict__ Wc16, float* __restrict__ b0, float* __restrict__ b1,
                    float* __restrict__ bc)
{
    const int tid = threadIdx.x, bid = blockIdx.x;
    if (bid == 0) {
        for (int i = tid; i < 512; i += 256) { b0[i] = bih0[i] + bhh0[i]; b1[i] = bih1[i] + bhh1[i]; }
        for (int i = tid; i < 512 * 32; i += 256) {
            int r = i >> 5, k = i & 31;
            W0h[i] = __float2half(k < 30 ? Wih0[r * 30 + k] : 0.f);
        }
        for (int i = tid; i < 64 * 128; i += 256) {
            int j = i >> 7, k = i & 127;
            float a = 0.f;
            if (j < 63) for (int m = 0; m < 84; ++m) a += Wo[j * 84 + m] * Wl[m * 128 + k];
            Wc16[i] = __float2half(a);
        }
        if (tid < 64) {
            float a = 0.f;
            if (tid < 63) { a = bo[tid]; for (int m = 0; m < 84; ++m) a += Wo[tid * 84 + m] * bl[m]; }
            bc[tid] = a;
        }
    } else if (bid == 1) {
        for (int i = tid; i < 512 * 128; i += 256) W1h[i] = __float2half(Wih1[i]);
    } else if (bid == 2) {
        for (int i = tid; i < 512 * 128; i += 256) Whh0h[i] = __float2half(Whh0[i]);
    } else if (bid == 3) {
        for (int i = tid; i < 512 * 128; i += 256) Whh1h[i] = __float2half(Whh1[i]);
    } else {
        const int base = (bid - 4) * 256;  // row base
        const float* xs = x + (size_t)base * 30;
        for (int i = tid; i < 256 * 30; i += 256) {
            int r = i / 30, k = i - r * 30;
            x16[(size_t)(base + r) * 32 + k] = __float2half(xs[i]);
        }
        for (int i = tid; i < 512; i += 256) {
            int r = i >> 1, k = 30 + (i & 1);
            x16[(size_t)(base + r) * 32 + k] = __float2half(0.f);
        }
    }
}

// ---------- projection GEMM with gate-interleaved output: xp[m][4j+q] ----------
template<int KK>
__global__ __launch_bounds__(256, 4)
void proj512_kernel(const __half* __restrict__ in, const __half* __restrict__ W16,
                    const float* __restrict__ bias, __half* __restrict__ xp)
{
    constexpr int KT = KK / 32;
    const int lane = threadIdx.x & 63;
    const int wn = threadIdx.x >> 6;     // 0..3
    const int rowbase = blockIdx.x * 32; // ROWT=2
    const int l15 = lane & 15, qg = lane >> 4, lk = qg * 8;

    float bs[2][4];
#pragma unroll
    for (int jt = 0; jt < 2; ++jt)
#pragma unroll
        for (int q = 0; q < 4; ++q)
            bs[jt][q] = bias[q * 128 + (2 * wn + jt) * 16 + l15];

    f32x4 acc[2][4][2];  // [jt][q][rt]
#pragma unroll
    for (int jt = 0; jt < 2; ++jt)
#pragma unroll
        for (int q = 0; q < 4; ++q)
#pragma unroll
            for (int rt = 0; rt < 2; ++rt) acc[jt][q][rt] = (f32x4){0.f, 0.f, 0.f, 0.f};

#pragma unroll
    for (int kt = 0; kt < KT; ++kt) {
        f16x8 a[2];
#pragma unroll
        for (int rt = 0; rt < 2; ++rt)
            a[rt] = *reinterpret_cast<const f16x8*>(in + (size_t)(rowbase + rt * 16 + l15) * KK + kt * 32 + lk);
#pragma unroll
        for (int jt = 0; jt < 2; ++jt)
#pragma unroll
            for (int q = 0; q < 4; ++q) {
                f16x8 bv = *reinterpret_cast<const f16x8*>(
                    W16 + (size_t)(q * 128 + (2 * wn + jt) * 16 + l15) * KK + kt * 32 + lk);
#pragma unroll
                for (int rt = 0; rt < 2; ++rt)
                    acc[jt][q][rt] = __builtin_amdgcn_mfma_f32_16x16x32_f16(a[rt], bv, acc[jt][q][rt], 0, 0, 0);
            }
    }
#pragma unroll
    for (int jt = 0; jt < 2; ++jt) {
        const int jg = (2 * wn + jt) * 16 + l15;
#pragma unroll
        for (int rt = 0; rt < 2; ++rt)
#pragma unroll
            for (int r = 0; r < 4; ++r) {
                const int m = rowbase + rt * 16 + qg * 4 + r;
                __half2 lo = __floats2half2_rn(acc[jt][0][rt][r] + bs[jt][0], acc[jt][1][rt][r] + bs[jt][1]);
                __half2 hi = __floats2half2_rn(acc[jt][2][rt][r] + bs[jt][2], acc[jt][3][rt][r] + bs[jt][3]);
                uint2 pk;
                pk.x = __builtin_bit_cast(unsigned, lo);
                pk.y = __builtin_bit_cast(unsigned, hi);
                *reinterpret_cast<uint2*>(xp + (size_t)m * 512 + 4 * jg) = pk;
            }
    }
}

// ---------- recurrence via MFMA: 4 batches/block (C rows 0,4,8,12), 1 act item/lane ----------
__global__ __launch_bounds__(512, 1)
void lstm_rec_mfma(const __half* __restrict__ xp, const __half* __restrict__ Whh16,
                   __half* __restrict__ hout)
{
    const int bb = blockIdx.x;       // 0..63, 4 batches each
    const int tid = threadIdx.x;
    const int w = tid >> 6;          // wave 0..7 -> units 16w..16w+15
    const int lane = tid & 63;
    const int l15 = lane & 15, qg = lane >> 4;
    const int j = w * 16 + l15;      // this lane's unit
    const int b = bb * 4 + qg;       // this lane's batch (C row qg*4, reg 0)

    // B-fragments of Whh (gate q, unit j): 64 VGPRs, loaded once
    f16x8 wb[4][4];
#pragma unroll
    for (int q = 0; q < 4; ++q)
#pragma unroll
        for (int kt = 0; kt < 4; ++kt)
            wb[q][kt] = *reinterpret_cast<const f16x8*>(
                Whh16 + (size_t)(q * 128 + j) * 128 + kt * 32 + qg * 8);

    // double-buffered h tile, 16 A-rows (only rows 0,4,8,12 ever nonzero), XOR-swizzled
    __shared__ __align__(16) __half hbuf[2][16 * 128];
    for (int i = tid; i < 2 * 16 * 128; i += 512) hbuf[0][i] = __float2half(0.f);

    const size_t xbase = (size_t)b * ((size_t)T_ * 512) + 4 * j;
    uint2 xq0 = *reinterpret_cast<const uint2*>(xp + xbase);          // t=0
    uint2 xq1 = *reinterpret_cast<const uint2*>(xp + xbase + 512);    // t=1
    float c = 0.f;
    __half* hop = hout + (size_t)b * T_ * H_ + j;
    __syncthreads();

    char* rd = (char*)&hbuf[0][0];
    char* wr = (char*)&hbuf[1][0];
    for (int t = 0; t < T_; ++t) {
        // A-fragments: h rows (batches at rows 0,4,8,12), swizzled
        f16x8 a[4];
#pragma unroll
        for (int kt = 0; kt < 4; ++kt) {
            int byte = (l15 * 256 + kt * 64 + qg * 16) ^ ((l15 & 7) << 4);
            a[kt] = *reinterpret_cast<const f16x8*>(rd + byte);
        }
        // prefetch t+2 (2-deep to cover HBM latency)
        uint2 xq2 = {0u, 0u};
        if (t + 2 < T_) xq2 = *reinterpret_cast<const uint2*>(xp + xbase + (size_t)(t + 2) * 512);

        // acc init: row 0 (this lane's batch) = xp gates; other rows 0 (A rows are zero there)
        f32x4 acc[4];
        {
            float2 flo = __half22float2(__builtin_bit_cast(__half2, xq0.x));
            float2 fhi = __half22float2(__builtin_bit_cast(__half2, xq0.y));
            acc[0] = (f32x4){flo.x, 0.f, 0.f, 0.f};
            acc[1] = (f32x4){flo.y, 0.f, 0.f, 0.f};
            acc[2] = (f32x4){fhi.x, 0.f, 0.f, 0.f};
            acc[3] = (f32x4){fhi.y, 0.f, 0.f, 0.f};
        }
#pragma unroll
        for (int kt = 0; kt < 4; ++kt)
#pragma unroll
            for (int q = 0; q < 4; ++q)
                acc[q] = __builtin_amdgcn_mfma_f32_16x16x32_f16(a[kt], wb[q][kt], acc[q], 0, 0, 0);

        // cell update: exactly one item per lane (batch b, unit j)
        float iv = sigmoid_f(acc[0][0]);
        float fv = sigmoid_f(acc[1][0]);
        float gv = tanh_f(acc[2][0]);
        float ov = sigmoid_f(acc[3][0]);
        c = fv * c + iv * gv;
        float h = ov * tanh_f(c);
        __half hh = __float2half(h);

        // write h into next buffer (A row qg*4, swizzled) + global
        {
            int row = qg * 4;
            int byte = (row * 256 + j * 2) ^ ((row & 7) << 4);
            *reinterpret_cast<__half*>(wr + byte) = hh;
        }
        hop[(size_t)t * H_] = hh;
        __syncthreads();
        char* tmp = rd; rd = wr; wr = tmp;
        xq0 = xq1; xq1 = xq2;
    }
}

// ---------- head: out = h2 @ Wc^T + bc (63 cols, f32) ----------
__global__ __launch_bounds__(256, 4)
void head_kernel(const __half* __restrict__ in, const __half* __restrict__ W16,
                 const float* __restrict__ bias, float* __restrict__ outp)
{
    constexpr int KK = 128;
    const int lane = threadIdx.x & 63;
    const int wn = threadIdx.x >> 6;
    const int rowbase = blockIdx.x * 64;  // ROWT=4
    const int colbase = wn * 16;
    const int l15 = lane & 15, lk = (lane >> 4) * 8;

    float bcol = bias[colbase + l15];
    f32x4 acc[4];
#pragma unroll
    for (int rt = 0; rt < 4; ++rt) acc[rt] = (f32x4){0.f, 0.f, 0.f, 0.f};

#pragma unroll
    for (int kt = 0; kt < 4; ++kt) {
        f16x8 bv = *reinterpret_cast<const f16x8*>(W16 + (size_t)(colbase + l15) * KK + kt * 32 + lk);
#pragma unroll
        for (int rt = 0; rt < 4; ++rt) {
            f16x8 a = *reinterpret_cast<const f16x8*>(in + (size_t)(rowbase + rt * 16 + l15) * KK + kt * 32 + lk);
            acc[rt] = __builtin_amdgcn_mfma_f32_16x16x32_f16(a, bv, acc[rt], 0, 0, 0);
        }
    }
    const int col = colbase + l15;
#pragma unroll
    for (int rt = 0; rt < 4; ++rt)
#pragma unroll
        for (int r = 0; r < 4; ++r) {
            const int row = rowbase + rt * 16 + (lane >> 4) * 4 + r;
            if (col < 63) outp[(size_t)row * 63 + col] = acc[rt][r] + bcol;
        }
}

extern "C" void kernel_launch(void* const* d_in, const int* in_sizes, int n_in,
                              void* d_out, int out_size, void* d_ws, size_t ws_size,
                              hipStream_t stream)
{
    const float* x    = (const float*)d_in[0];
    const float* Wih0 = (const float*)d_in[1];
    const float* Whh0 = (const float*)d_in[2];
    const float* bih0 = (const float*)d_in[3];
    const float* bhh0 = (const float*)d_in[4];
    const float* Wih1 = (const float*)d_in[5];
    const float* Whh1 = (const float*)d_in[6];
    const float* bih1 = (const float*)d_in[7];
    const float* bhh1 = (const float*)d_in[8];
    const float* Wl   = (const float*)d_in[9];
    const float* bl   = (const float*)d_in[10];
    const float* Wo   = (const float*)d_in[11];
    const float* bo   = (const float*)d_in[12];
    float* out = (float*)d_out;

    char* ws = (char*)d_ws;
    size_t off = 0;
    auto carve = [&](size_t bytes) { void* p = ws + off; off += (bytes + 255) & ~(size_t)255; return p; };
    __half* xp  = (__half*)carve((size_t)M_ * 512 * 2);  // 134 MB, shared by both layers
    __half* h1  = (__half*)carve((size_t)M_ * 128 * 2);  // 33.5 MB
    __half* h2  = (__half*)carve((size_t)M_ * 128 * 2);  // 33.5 MB
    __half* x16 = h2;                                    // alias: x16 dead before h2 written
    __half* W0h   = (__half*)carve(512 * 32 * 2);
    __half* W1h   = (__half*)carve(512 * 128 * 2);
    __half* Whh0h = (__half*)carve(512 * 128 * 2);
    __half* Whh1h = (__half*)carve(512 * 128 * 2);
    __half* Wc16  = (__half*)carve(64 * 128 * 2);
    float*  b0    = (float*)carve(512 * 4);
    float*  b1    = (float*)carve(512 * 4);
    float*  bc    = (float*)carve(64 * 4);

    hipLaunchKernelGGL(convert_kernel, dim3(4 + M_ / 256), dim3(256), 0, stream,
                       x, Wih0, bih0, bhh0, Whh0, Whh1, Wih1, bih1, bhh1, Wl, bl, Wo, bo,
                       x16, W0h, W1h, Whh0h, Whh1h, Wc16, b0, b1, bc);

    // layer 0
    hipLaunchKernelGGL((proj512_kernel<32>), dim3(M_ / 32), dim3(256), 0, stream,
                       x16, W0h, b0, xp);
    hipLaunchKernelGGL(lstm_rec_mfma, dim3(64), dim3(512), 0, stream, xp, Whh0h, h1);

    // layer 1
    hipLaunchKernelGGL((proj512_kernel<128>), dim3(M_ / 32), dim3(256), 0, stream,
                       h1, W1h, b1, xp);
    hipLaunchKernelGGL(lstm_rec_mfma, dim3(64), dim3(512), 0, stream, xp, Whh1h, h2);

    // head
    hipLaunchKernelGGL(head_kernel, dim3(M_ / 64), dim3(256), 0, stream,
                       h2, Wc16, bc, out);
}

// Round 5
// 775.786 us; speedup vs baseline: 2.5044x; 1.1721x over previous
//
#include <hip/hip_runtime.h>
#include <hip/hip_fp16.h>

#define B_ 256
#define T_ 512
#define H_ 128
#define M_ (B_ * T_)  // 131072 rows

typedef _Float16 f16x8 __attribute__((ext_vector_type(8)));
typedef float    f32x4 __attribute__((ext_vector_type(4)));

__device__ __forceinline__ float rcp_f(float a) { return __builtin_amdgcn_rcpf(a); }
__device__ __forceinline__ float sigmoid_f(float a) { return rcp_f(1.f + __expf(-a)); }
__device__ __forceinline__ float tanh_f(float a) { return 1.f - 2.f * rcp_f(__expf(2.f * a) + 1.f); }

// Barrier that drains ONLY LDS (lgkmcnt), not vmcnt: lets global prefetches and
// stores stay in flight across steps. __syncthreads() would drain vmcnt(0) and
// serialize the HBM prefetch into every step (~900 cy/step stall).
__device__ __forceinline__ void lds_barrier() {
    asm volatile("s_waitcnt lgkmcnt(0)\n\ts_barrier" ::: "memory");
}

// ---------- one-time conversions ----------
__global__ __launch_bounds__(256)
void convert_kernel(const float* __restrict__ x,
                    const float* __restrict__ Wih0, const float* __restrict__ bih0, const float* __restrict__ bhh0,
                    const float* __restrict__ Whh0, const float* __restrict__ Whh1,
                    const float* __restrict__ Wih1, const float* __restrict__ bih1, const float* __restrict__ bhh1,
                    const float* __restrict__ Wl, const float* __restrict__ bl,
                    const float* __restrict__ Wo, const float* __restrict__ bo,
                    __half* __restrict__ x16, __half* __restrict__ W0h, __half* __restrict__ W1h,
                    __half* __restrict__ Whh0h, __half* __restrict__ Whh1h,
                    __half* __restrict__ Wc16, float* __restrict__ b0, float* __restrict__ b1,
                    float* __restrict__ bc)
{
    const int tid = threadIdx.x, bid = blockIdx.x;
    if (bid == 0) {
        for (int i = tid; i < 512; i += 256) { b0[i] = bih0[i] + bhh0[i]; b1[i] = bih1[i] + bhh1[i]; }
        for (int i = tid; i < 512 * 32; i += 256) {
            int r = i >> 5, k = i & 31;
            W0h[i] = __float2half(k < 30 ? Wih0[r * 30 + k] : 0.f);
        }
        for (int i = tid; i < 64 * 128; i += 256) {
            int j = i >> 7, k = i & 127;
            float a = 0.f;
            if (j < 63) for (int m = 0; m < 84; ++m) a += Wo[j * 84 + m] * Wl[m * 128 + k];
            Wc16[i] = __float2half(a);
        }
        if (tid < 64) {
            float a = 0.f;
            if (tid < 63) { a = bo[tid]; for (int m = 0; m < 84; ++m) a += Wo[tid * 84 + m] * bl[m]; }
            bc[tid] = a;
        }
    } else if (bid == 1) {
        for (int i = tid; i < 512 * 128; i += 256) W1h[i] = __float2half(Wih1[i]);
    } else if (bid == 2) {
        for (int i = tid; i < 512 * 128; i += 256) Whh0h[i] = __float2half(Whh0[i]);
    } else if (bid == 3) {
        for (int i = tid; i < 512 * 128; i += 256) Whh1h[i] = __float2half(Whh1[i]);
    } else {
        const int base = (bid - 4) * 256;  // row base
        const float* xs = x + (size_t)base * 30;
        for (int i = tid; i < 256 * 30; i += 256) {
            int r = i / 30, k = i - r * 30;
            x16[(size_t)(base + r) * 32 + k] = __float2half(xs[i]);
        }
        for (int i = tid; i < 512; i += 256) {
            int r = i >> 1, k = 30 + (i & 1);
            x16[(size_t)(base + r) * 32 + k] = __float2half(0.f);
        }
    }
}

// ---------- projection GEMM with gate-interleaved output: xp[m][4j+q] ----------
template<int KK>
__global__ __launch_bounds__(256, 4)
void proj512_kernel(const __half* __restrict__ in, const __half* __restrict__ W16,
                    const float* __restrict__ bias, __half* __restrict__ xp)
{
    constexpr int KT = KK / 32;
    const int lane = threadIdx.x & 63;
    const int wn = threadIdx.x >> 6;     // 0..3
    const int rowbase = blockIdx.x * 32; // ROWT=2
    const int l15 = lane & 15, qg = lane >> 4, lk = qg * 8;

    float bs[2][4];
#pragma unroll
    for (int jt = 0; jt < 2; ++jt)
#pragma unroll
        for (int q = 0; q < 4; ++q)
            bs[jt][q] = bias[q * 128 + (2 * wn + jt) * 16 + l15];

    f32x4 acc[2][4][2];  // [jt][q][rt]
#pragma unroll
    for (int jt = 0; jt < 2; ++jt)
#pragma unroll
        for (int q = 0; q < 4; ++q)
#pragma unroll
            for (int rt = 0; rt < 2; ++rt) acc[jt][q][rt] = (f32x4){0.f, 0.f, 0.f, 0.f};

#pragma unroll
    for (int kt = 0; kt < KT; ++kt) {
        f16x8 a[2];
#pragma unroll
        for (int rt = 0; rt < 2; ++rt)
            a[rt] = *reinterpret_cast<const f16x8*>(in + (size_t)(rowbase + rt * 16 + l15) * KK + kt * 32 + lk);
#pragma unroll
        for (int jt = 0; jt < 2; ++jt)
#pragma unroll
            for (int q = 0; q < 4; ++q) {
                f16x8 bv = *reinterpret_cast<const f16x8*>(
                    W16 + (size_t)(q * 128 + (2 * wn + jt) * 16 + l15) * KK + kt * 32 + lk);
#pragma unroll
                for (int rt = 0; rt < 2; ++rt)
                    acc[jt][q][rt] = __builtin_amdgcn_mfma_f32_16x16x32_f16(a[rt], bv, acc[jt][q][rt], 0, 0, 0);
            }
    }
#pragma unroll
    for (int jt = 0; jt < 2; ++jt) {
        const int jg = (2 * wn + jt) * 16 + l15;
#pragma unroll
        for (int rt = 0; rt < 2; ++rt)
#pragma unroll
            for (int r = 0; r < 4; ++r) {
                const int m = rowbase + rt * 16 + qg * 4 + r;
                __half2 lo = __floats2half2_rn(acc[jt][0][rt][r] + bs[jt][0], acc[jt][1][rt][r] + bs[jt][1]);
                __half2 hi = __floats2half2_rn(acc[jt][2][rt][r] + bs[jt][2], acc[jt][3][rt][r] + bs[jt][3]);
                uint2 pk;
                pk.x = __builtin_bit_cast(unsigned, lo);
                pk.y = __builtin_bit_cast(unsigned, hi);
                *reinterpret_cast<uint2*>(xp + (size_t)m * 512 + 4 * jg) = pk;
            }
    }
}

// ---------- recurrence via MFMA: 4 batches/block (C rows 0,4,8,12), 1 act item/lane ----------
__global__ __launch_bounds__(512, 1)
void lstm_rec_mfma(const __half* __restrict__ xp, const __half* __restrict__ Whh16,
                   __half* __restrict__ hout)
{
    const int bb = blockIdx.x;       // 0..63, 4 batches each
    const int tid = threadIdx.x;
    const int w = tid >> 6;          // wave 0..7 -> units 16w..16w+15
    const int lane = tid & 63;
    const int l15 = lane & 15, qg = lane >> 4;
    const int j = w * 16 + l15;      // this lane's unit
    const int b = bb * 4 + qg;       // this lane's batch (C row qg*4, reg 0)

    // B-fragments of Whh (gate q, unit j): 64 VGPRs, loaded once
    f16x8 wb[4][4];
#pragma unroll
    for (int q = 0; q < 4; ++q)
#pragma unroll
        for (int kt = 0; kt < 4; ++kt)
            wb[q][kt] = *reinterpret_cast<const f16x8*>(
                Whh16 + (size_t)(q * 128 + j) * 128 + kt * 32 + qg * 8);

    // double-buffered h tile, 16 A-rows (only rows 0,4,8,12 ever nonzero), XOR-swizzled
    __shared__ __align__(16) __half hbuf[2][16 * 128];
    for (int i = tid; i < 2 * 16 * 128; i += 512) hbuf[0][i] = __float2half(0.f);

    const size_t xbase = (size_t)b * ((size_t)T_ * 512) + 4 * j;
    uint2 xq0 = *reinterpret_cast<const uint2*>(xp + xbase);          // t=0
    uint2 xq1 = *reinterpret_cast<const uint2*>(xp + xbase + 512);    // t=1
    float c = 0.f;
    __half* hop = hout + (size_t)b * T_ * H_ + j;
    __syncthreads();

    char* rd = (char*)&hbuf[0][0];
    char* wr = (char*)&hbuf[1][0];
    for (int t = 0; t < T_; ++t) {
        // A-fragments: h rows (batches at rows 0,4,8,12), swizzled
        f16x8 a[4];
#pragma unroll
        for (int kt = 0; kt < 4; ++kt) {
            int byte = (l15 * 256 + kt * 64 + qg * 16) ^ ((l15 & 7) << 4);
            a[kt] = *reinterpret_cast<const f16x8*>(rd + byte);
        }
        // prefetch t+2 (2-deep; never drained thanks to lds_barrier)
        uint2 xq2 = {0u, 0u};
        if (t + 2 < T_) xq2 = *reinterpret_cast<const uint2*>(xp + xbase + (size_t)(t + 2) * 512);

        // acc init: row 0 (this lane's batch) = xp gates; other rows 0 (A rows are zero there)
        f32x4 acc[4];
        {
            float2 flo = __half22float2(__builtin_bit_cast(__half2, xq0.x));
            float2 fhi = __half22float2(__builtin_bit_cast(__half2, xq0.y));
            acc[0] = (f32x4){flo.x, 0.f, 0.f, 0.f};
            acc[1] = (f32x4){flo.y, 0.f, 0.f, 0.f};
            acc[2] = (f32x4){fhi.x, 0.f, 0.f, 0.f};
            acc[3] = (f32x4){fhi.y, 0.f, 0.f, 0.f};
        }
#pragma unroll
        for (int kt = 0; kt < 4; ++kt)
#pragma unroll
            for (int q = 0; q < 4; ++q)
                acc[q] = __builtin_amdgcn_mfma_f32_16x16x32_f16(a[kt], wb[q][kt], acc[q], 0, 0, 0);

        // cell update: exactly one item per lane (batch b, unit j)
        float iv = sigmoid_f(acc[0][0]);
        float fv = sigmoid_f(acc[1][0]);
        float gv = tanh_f(acc[2][0]);
        float ov = sigmoid_f(acc[3][0]);
        c = fv * c + iv * gv;
        float h = ov * tanh_f(c);
        __half hh = __float2half(h);

        // write h into next buffer (A row qg*4, swizzled) + global (store floats)
        {
            int row = qg * 4;
            int byte = (row * 256 + j * 2) ^ ((row & 7) << 4);
            *reinterpret_cast<__half*>(wr + byte) = hh;
        }
        hop[(size_t)t * H_] = hh;
        lds_barrier();   // LDS-only drain: vmem stays in flight
        char* tmp = rd; rd = wr; wr = tmp;
        xq0 = xq1; xq1 = xq2;
    }
}

// ---------- head: out = h2 @ Wc^T + bc (63 cols, f32) ----------
__global__ __launch_bounds__(256, 4)
void head_kernel(const __half* __restrict__ in, const __half* __restrict__ W16,
                 const float* __restrict__ bias, float* __restrict__ outp)
{
    constexpr int KK = 128;
    const int lane = threadIdx.x & 63;
    const int wn = threadIdx.x >> 6;
    const int rowbase = blockIdx.x * 64;  // ROWT=4
    const int colbase = wn * 16;
    const int l15 = lane & 15, lk = (lane >> 4) * 8;

    float bcol = bias[colbase + l15];
    f32x4 acc[4];
#pragma unroll
    for (int rt = 0; rt < 4; ++rt) acc[rt] = (f32x4){0.f, 0.f, 0.f, 0.f};

#pragma unroll
    for (int kt = 0; kt < 4; ++kt) {
        f16x8 bv = *reinterpret_cast<const f16x8*>(W16 + (size_t)(colbase + l15) * KK + kt * 32 + lk);
#pragma unroll
        for (int rt = 0; rt < 4; ++rt) {
            f16x8 a = *reinterpret_cast<const f16x8*>(in + (size_t)(rowbase + rt * 16 + l15) * KK + kt * 32 + lk);
            acc[rt] = __builtin_amdgcn_mfma_f32_16x16x32_f16(a, bv, acc[rt], 0, 0, 0);
        }
    }
    const int col = colbase + l15;
#pragma unroll
    for (int rt = 0; rt < 4; ++rt)
#pragma unroll
        for (int r = 0; r < 4; ++r) {
            const int row = rowbase + rt * 16 + (lane >> 4) * 4 + r;
            if (col < 63) outp[(size_t)row * 63 + col] = acc[rt][r] + bcol;
        }
}

extern "C" void kernel_launch(void* const* d_in, const int* in_sizes, int n_in,
                              void* d_out, int out_size, void* d_ws, size_t ws_size,
                              hipStream_t stream)
{
    const float* x    = (const float*)d_in[0];
    const float* Wih0 = (const float*)d_in[1];
    const float* Whh0 = (const float*)d_in[2];
    const float* bih0 = (const float*)d_in[3];
    const float* bhh0 = (const float*)d_in[4];
    const float* Wih1 = (const float*)d_in[5];
    const float* Whh1 = (const float*)d_in[6];
    const float* bih1 = (const float*)d_in[7];
    const float* bhh1 = (const float*)d_in[8];
    const float* Wl   = (const float*)d_in[9];
    const float* bl   = (const float*)d_in[10];
    const float* Wo   = (const float*)d_in[11];
    const float* bo   = (const float*)d_in[12];
    float* out = (float*)d_out;

    char* ws = (char*)d_ws;
    size_t off = 0;
    auto carve = [&](size_t bytes) { void* p = ws + off; off += (bytes + 255) & ~(size_t)255; return p; };
    __half* xp  = (__half*)carve((size_t)M_ * 512 * 2);  // 134 MB, shared by both layers
    __half* h1  = (__half*)carve((size_t)M_ * 128 * 2);  // 33.5 MB
    __half* h2  = (__half*)carve((size_t)M_ * 128 * 2);  // 33.5 MB
    __half* x16 = h2;                                    // alias: x16 dead before h2 written
    __half* W0h   = (__half*)carve(512 * 32 * 2);
    __half* W1h   = (__half*)carve(512 * 128 * 2);
    __half* Whh0h = (__half*)carve(512 * 128 * 2);
    __half* Whh1h = (__half*)carve(512 * 128 * 2);
    __half* Wc16  = (__half*)carve(64 * 128 * 2);
    float*  b0    = (float*)carve(512 * 4);
    float*  b1    = (float*)carve(512 * 4);
    float*  bc    = (float*)carve(64 * 4);

    hipLaunchKernelGGL(convert_kernel, dim3(4 + M_ / 256), dim3(256), 0, stream,
                       x, Wih0, bih0, bhh0, Whh0, Whh1, Wih1, bih1, bhh1, Wl, bl, Wo, bo,
                       x16, W0h, W1h, Whh0h, Whh1h, Wc16, b0, b1, bc);

    // layer 0
    hipLaunchKernelGGL((proj512_kernel<32>), dim3(M_ / 32), dim3(256), 0, stream,
                       x16, W0h, b0, xp);
    hipLaunchKernelGGL(lstm_rec_mfma, dim3(64), dim3(512), 0, stream, xp, Whh0h, h1);

    // layer 1
    hipLaunchKernelGGL((proj512_kernel<128>), dim3(M_ / 32), dim3(256), 0, stream,
                       h1, W1h, b1, xp);
    hipLaunchKernelGGL(lstm_rec_mfma, dim3(64), dim3(512), 0, stream, xp, Whh1h, h2);

    // head
    hipLaunchKernelGGL(head_kernel, dim3(M_ / 64), dim3(256), 0, stream,
                       h2, Wc16, bc, out);
}

// Round 6
// 682.024 us; speedup vs baseline: 2.8487x; 1.1375x over previous
//
#include <hip/hip_runtime.h>
#include <hip/hip_fp16.h>

#define B_ 256
#define T_ 512
#define H_ 128
#define M_ (B_ * T_)  // 131072 rows

typedef _Float16 f16x8 __attribute__((ext_vector_type(8)));
typedef float    f32x4 __attribute__((ext_vector_type(4)));

__device__ __forceinline__ float rcp_f(float a) { return __builtin_amdgcn_rcpf(a); }
__device__ __forceinline__ float sigmoid_f(float a) { return rcp_f(1.f + __expf(-a)); }
__device__ __forceinline__ float tanh_f(float a) { return 1.f - 2.f * rcp_f(__expf(2.f * a) + 1.f); }

// Barrier that drains ONLY LDS (lgkmcnt), not vmcnt: lets global prefetches and
// stores stay in flight across steps (T4 discipline: never vmcnt(0) in the loop).
__device__ __forceinline__ void lds_barrier() {
    asm volatile("s_waitcnt lgkmcnt(0)\n\ts_barrier" ::: "memory");
}

// ---------- one-time conversions ----------
__global__ __launch_bounds__(256)
void convert_kernel(const float* __restrict__ x,
                    const float* __restrict__ Wih0, const float* __restrict__ bih0, const float* __restrict__ bhh0,
                    const float* __restrict__ Whh0, const float* __restrict__ Whh1,
                    const float* __restrict__ Wih1, const float* __restrict__ bih1, const float* __restrict__ bhh1,
                    const float* __restrict__ Wl, const float* __restrict__ bl,
                    const float* __restrict__ Wo, const float* __restrict__ bo,
                    __half* __restrict__ x16, __half* __restrict__ W0h, __half* __restrict__ W1h,
                    __half* __restrict__ Whh0h, __half* __restrict__ Whh1h,
                    __half* __restrict__ Wc16, float* __restrict__ b0, float* __restrict__ b1,
                    float* __restrict__ bc)
{
    const int tid = threadIdx.x, bid = blockIdx.x;
    if (bid == 0) {
        for (int i = tid; i < 512; i += 256) { b0[i] = bih0[i] + bhh0[i]; b1[i] = bih1[i] + bhh1[i]; }
        for (int i = tid; i < 512 * 32; i += 256) {
            int r = i >> 5, k = i & 31;
            W0h[i] = __float2half(k < 30 ? Wih0[r * 30 + k] : 0.f);
        }
        for (int i = tid; i < 64 * 128; i += 256) {
            int j = i >> 7, k = i & 127;
            float a = 0.f;
            if (j < 63) for (int m = 0; m < 84; ++m) a += Wo[j * 84 + m] * Wl[m * 128 + k];
            Wc16[i] = __float2half(a);
        }
        if (tid < 64) {
            float a = 0.f;
            if (tid < 63) { a = bo[tid]; for (int m = 0; m < 84; ++m) a += Wo[tid * 84 + m] * bl[m]; }
            bc[tid] = a;
        }
    } else if (bid == 1) {
        for (int i = tid; i < 512 * 128; i += 256) W1h[i] = __float2half(Wih1[i]);
    } else if (bid == 2) {
        for (int i = tid; i < 512 * 128; i += 256) Whh0h[i] = __float2half(Whh0[i]);
    } else if (bid == 3) {
        for (int i = tid; i < 512 * 128; i += 256) Whh1h[i] = __float2half(Whh1[i]);
    } else {
        const int base = (bid - 4) * 256;  // row base
        const float* xs = x + (size_t)base * 30;
        for (int i = tid; i < 256 * 30; i += 256) {
            int r = i / 30, k = i - r * 30;
            x16[(size_t)(base + r) * 32 + k] = __float2half(xs[i]);
        }
        for (int i = tid; i < 512; i += 256) {
            int r = i >> 1, k = 30 + (i & 1);
            x16[(size_t)(base + r) * 32 + k] = __float2half(0.f);
        }
    }
}

// ---------- projection GEMM with gate-interleaved output: xp[m][4j+q] ----------
template<int KK>
__global__ __launch_bounds__(256, 4)
void proj512_kernel(const __half* __restrict__ in, const __half* __restrict__ W16,
                    const float* __restrict__ bias, __half* __restrict__ xp)
{
    constexpr int KT = KK / 32;
    const int lane = threadIdx.x & 63;
    const int wn = threadIdx.x >> 6;     // 0..3
    const int rowbase = blockIdx.x * 32; // ROWT=2
    const int l15 = lane & 15, qg = lane >> 4, lk = qg * 8;

    float bs[2][4];
#pragma unroll
    for (int jt = 0; jt < 2; ++jt)
#pragma unroll
        for (int q = 0; q < 4; ++q)
            bs[jt][q] = bias[q * 128 + (2 * wn + jt) * 16 + l15];

    f32x4 acc[2][4][2];  // [jt][q][rt]
#pragma unroll
    for (int jt = 0; jt < 2; ++jt)
#pragma unroll
        for (int q = 0; q < 4; ++q)
#pragma unroll
            for (int rt = 0; rt < 2; ++rt) acc[jt][q][rt] = (f32x4){0.f, 0.f, 0.f, 0.f};

#pragma unroll
    for (int kt = 0; kt < KT; ++kt) {
        f16x8 a[2];
#pragma unroll
        for (int rt = 0; rt < 2; ++rt)
            a[rt] = *reinterpret_cast<const f16x8*>(in + (size_t)(rowbase + rt * 16 + l15) * KK + kt * 32 + lk);
#pragma unroll
        for (int jt = 0; jt < 2; ++jt)
#pragma unroll
            for (int q = 0; q < 4; ++q) {
                f16x8 bv = *reinterpret_cast<const f16x8*>(
                    W16 + (size_t)(q * 128 + (2 * wn + jt) * 16 + l15) * KK + kt * 32 + lk);
#pragma unroll
                for (int rt = 0; rt < 2; ++rt)
                    acc[jt][q][rt] = __builtin_amdgcn_mfma_f32_16x16x32_f16(a[rt], bv, acc[jt][q][rt], 0, 0, 0);
            }
    }
#pragma unroll
    for (int jt = 0; jt < 2; ++jt) {
        const int jg = (2 * wn + jt) * 16 + l15;
#pragma unroll
        for (int rt = 0; rt < 2; ++rt)
#pragma unroll
            for (int r = 0; r < 4; ++r) {
                const int m = rowbase + rt * 16 + qg * 4 + r;
                __half2 lo = __floats2half2_rn(acc[jt][0][rt][r] + bs[jt][0], acc[jt][1][rt][r] + bs[jt][1]);
                __half2 hi = __floats2half2_rn(acc[jt][2][rt][r] + bs[jt][2], acc[jt][3][rt][r] + bs[jt][3]);
                uint2 pk;
                pk.x = __builtin_bit_cast(unsigned, lo);
                pk.y = __builtin_bit_cast(unsigned, hi);
                *reinterpret_cast<uint2*>(xp + (size_t)m * 512 + 4 * jg) = pk;
            }
    }
}

// ---------- recurrence via MFMA: 4 batches/block, 8-deep named-register xp pipeline ----------
#define MFMA16(A, BV, C) __builtin_amdgcn_mfma_f32_16x16x32_f16((A), (BV), (C), 0, 0, 0)

#define STEP(XQ, RD, WR, TT) do {                                              \
    f16x8 a0 = *reinterpret_cast<const f16x8*>((RD) + ro0);                    \
    f16x8 a1 = *reinterpret_cast<const f16x8*>((RD) + ro1);                    \
    f16x8 a2 = *reinterpret_cast<const f16x8*>((RD) + ro2);                    \
    f16x8 a3 = *reinterpret_cast<const f16x8*>((RD) + ro3);                    \
    float2 flo = __half22float2(__builtin_bit_cast(__half2, XQ.x));            \
    float2 fhi = __half22float2(__builtin_bit_cast(__half2, XQ.y));            \
    XQ = *reinterpret_cast<const uint2*>(xp + xbase + (size_t)((TT) + 8) * 512); \
    f32x4 ac0 = (f32x4){flo.x, 0.f, 0.f, 0.f};                                 \
    f32x4 ac1 = (f32x4){flo.y, 0.f, 0.f, 0.f};                                 \
    f32x4 ac2 = (f32x4){fhi.x, 0.f, 0.f, 0.f};                                 \
    f32x4 ac3 = (f32x4){fhi.y, 0.f, 0.f, 0.f};                                 \
    ac0 = MFMA16(a0, wb[0][0], ac0); ac1 = MFMA16(a0, wb[1][0], ac1);          \
    ac2 = MFMA16(a0, wb[2][0], ac2); ac3 = MFMA16(a0, wb[3][0], ac3);          \
    ac0 = MFMA16(a1, wb[0][1], ac0); ac1 = MFMA16(a1, wb[1][1], ac1);          \
    ac2 = MFMA16(a1, wb[2][1], ac2); ac3 = MFMA16(a1, wb[3][1], ac3);          \
    ac0 = MFMA16(a2, wb[0][2], ac0); ac1 = MFMA16(a2, wb[1][2], ac1);          \
    ac2 = MFMA16(a2, wb[2][2], ac2); ac3 = MFMA16(a2, wb[3][2], ac3);          \
    ac0 = MFMA16(a3, wb[0][3], ac0); ac1 = MFMA16(a3, wb[1][3], ac1);          \
    ac2 = MFMA16(a3, wb[2][3], ac2); ac3 = MFMA16(a3, wb[3][3], ac3);          \
    float iv = sigmoid_f(ac0[0]);                                              \
    float fv = sigmoid_f(ac1[0]);                                              \
    float gv = tanh_f(ac2[0]);                                                 \
    float ov = sigmoid_f(ac3[0]);                                              \
    c = fv * c + iv * gv;                                                      \
    float hval = ov * tanh_f(c);                                               \
    __half hh = __float2half(hval);                                            \
    *reinterpret_cast<__half*>((WR) + wo) = hh;                                \
    hop[(size_t)(TT) * H_] = hh;                                               \
    lds_barrier();                                                             \
} while (0)

__global__ __launch_bounds__(512, 1)
void lstm_rec_mfma(const __half* __restrict__ xp, const __half* __restrict__ Whh16,
                   __half* __restrict__ hout)
{
    const int bb = blockIdx.x;       // 0..63, 4 batches each
    const int tid = threadIdx.x;
    const int w = tid >> 6;          // wave 0..7 -> units 16w..16w+15
    const int lane = tid & 63;
    const int l15 = lane & 15, qg = lane >> 4;
    const int j = w * 16 + l15;      // this lane's unit
    const int b = bb * 4 + qg;       // this lane's batch (C row qg*4, reg 0)

    // B-fragments of Whh (gate q, unit j): 64 VGPRs, loaded once
    f16x8 wb[4][4];
#pragma unroll
    for (int q = 0; q < 4; ++q)
#pragma unroll
        for (int kt = 0; kt < 4; ++kt)
            wb[q][kt] = *reinterpret_cast<const f16x8*>(
                Whh16 + (size_t)(q * 128 + j) * 128 + kt * 32 + qg * 8);

    // double-buffered h tile, 16 A-rows (only rows 0,4,8,12 ever nonzero), XOR-swizzled
    __shared__ __align__(16) __half hbuf[2][16 * 128];
    for (int i = tid; i < 2 * 16 * 128; i += 512) hbuf[0][i] = __float2half(0.f);

    // hoisted LDS offsets (swizzled)
    const int ro0 = (l15 * 256 + 0 * 64 + qg * 16) ^ ((l15 & 7) << 4);
    const int ro1 = (l15 * 256 + 1 * 64 + qg * 16) ^ ((l15 & 7) << 4);
    const int ro2 = (l15 * 256 + 2 * 64 + qg * 16) ^ ((l15 & 7) << 4);
    const int ro3 = (l15 * 256 + 3 * 64 + qg * 16) ^ ((l15 & 7) << 4);
    const int wo  = (qg * 4 * 256 + j * 2) ^ (((qg * 4) & 7) << 4);

    const size_t xbase = (size_t)b * ((size_t)T_ * 512) + 4 * j;
    // 8-deep named prefetch registers (unconditional; xp padded by 8 steps)
    uint2 x0 = *reinterpret_cast<const uint2*>(xp + xbase + 0 * 512);
    uint2 x1 = *reinterpret_cast<const uint2*>(xp + xbase + 1 * 512);
    uint2 x2 = *reinterpret_cast<const uint2*>(xp + xbase + 2 * 512);
    uint2 x3 = *reinterpret_cast<const uint2*>(xp + xbase + 3 * 512);
    uint2 x4 = *reinterpret_cast<const uint2*>(xp + xbase + 4 * 512);
    uint2 x5 = *reinterpret_cast<const uint2*>(xp + xbase + 5 * 512);
    uint2 x6 = *reinterpret_cast<const uint2*>(xp + xbase + 6 * 512);
    uint2 x7 = *reinterpret_cast<const uint2*>(xp + xbase + 7 * 512);
    float c = 0.f;
    __half* hop = hout + (size_t)b * T_ * H_ + j;
    __syncthreads();

    char* const rd0 = (char*)&hbuf[0][0];
    char* const rd1 = (char*)&hbuf[1][0];
    for (int tb = 0; tb < T_; tb += 8) {
        STEP(x0, rd0, rd1, tb + 0);
        STEP(x1, rd1, rd0, tb + 1);
        STEP(x2, rd0, rd1, tb + 2);
        STEP(x3, rd1, rd0, tb + 3);
        STEP(x4, rd0, rd1, tb + 4);
        STEP(x5, rd1, rd0, tb + 5);
        STEP(x6, rd0, rd1, tb + 6);
        STEP(x7, rd1, rd0, tb + 7);
    }
}

// ---------- head: out = h2 @ Wc^T + bc (63 cols, f32) ----------
__global__ __launch_bounds__(256, 4)
void head_kernel(const __half* __restrict__ in, const __half* __restrict__ W16,
                 const float* __restrict__ bias, float* __restrict__ outp)
{
    constexpr int KK = 128;
    const int lane = threadIdx.x & 63;
    const int wn = threadIdx.x >> 6;
    const int rowbase = blockIdx.x * 64;  // ROWT=4
    const int colbase = wn * 16;
    const int l15 = lane & 15, lk = (lane >> 4) * 8;

    float bcol = bias[colbase + l15];
    f32x4 acc[4];
#pragma unroll
    for (int rt = 0; rt < 4; ++rt) acc[rt] = (f32x4){0.f, 0.f, 0.f, 0.f};

#pragma unroll
    for (int kt = 0; kt < 4; ++kt) {
        f16x8 bv = *reinterpret_cast<const f16x8*>(W16 + (size_t)(colbase + l15) * KK + kt * 32 + lk);
#pragma unroll
        for (int rt = 0; rt < 4; ++rt) {
            f16x8 a = *reinterpret_cast<const f16x8*>(in + (size_t)(rowbase + rt * 16 + l15) * KK + kt * 32 + lk);
            acc[rt] = __builtin_amdgcn_mfma_f32_16x16x32_f16(a, bv, acc[rt], 0, 0, 0);
        }
    }
    const int col = colbase + l15;
#pragma unroll
    for (int rt = 0; rt < 4; ++rt)
#pragma unroll
        for (int r = 0; r < 4; ++r) {
            const int row = rowbase + rt * 16 + (lane >> 4) * 4 + r;
            if (col < 63) outp[(size_t)row * 63 + col] = acc[rt][r] + bcol;
        }
}

extern "C" void kernel_launch(void* const* d_in, const int* in_sizes, int n_in,
                              void* d_out, int out_size, void* d_ws, size_t ws_size,
                              hipStream_t stream)
{
    const float* x    = (const float*)d_in[0];
    const float* Wih0 = (const float*)d_in[1];
    const float* Whh0 = (const float*)d_in[2];
    const float* bih0 = (const float*)d_in[3];
    const float* bhh0 = (const float*)d_in[4];
    const float* Wih1 = (const float*)d_in[5];
    const float* Whh1 = (const float*)d_in[6];
    const float* bih1 = (const float*)d_in[7];
    const float* bhh1 = (const float*)d_in[8];
    const float* Wl   = (const float*)d_in[9];
    const float* bl   = (const float*)d_in[10];
    const float* Wo   = (const float*)d_in[11];
    const float* bo   = (const float*)d_in[12];
    float* out = (float*)d_out;

    char* ws = (char*)d_ws;
    size_t off = 0;
    auto carve = [&](size_t bytes) { void* p = ws + off; off += (bytes + 255) & ~(size_t)255; return p; };
    __half* xp  = (__half*)carve(((size_t)M_ * 512 + 8 * 512) * 2);  // 134 MB + 8-step pad
    __half* h1  = (__half*)carve((size_t)M_ * 128 * 2);  // 33.5 MB
    __half* h2  = (__half*)carve((size_t)M_ * 128 * 2);  // 33.5 MB
    __half* x16 = h2;                                    // alias: x16 dead before h2 written
    __half* W0h   = (__half*)carve(512 * 32 * 2);
    __half* W1h   = (__half*)carve(512 * 128 * 2);
    __half* Whh0h = (__half*)carve(512 * 128 * 2);
    __half* Whh1h = (__half*)carve(512 * 128 * 2);
    __half* Wc16  = (__half*)carve(64 * 128 * 2);
    float*  b0    = (float*)carve(512 * 4);
    float*  b1    = (float*)carve(512 * 4);
    float*  bc    = (float*)carve(64 * 4);

    hipLaunchKernelGGL(convert_kernel, dim3(4 + M_ / 256), dim3(256), 0, stream,
                       x, Wih0, bih0, bhh0, Whh0, Whh1, Wih1, bih1, bhh1, Wl, bl, Wo, bo,
                       x16, W0h, W1h, Whh0h, Whh1h, Wc16, b0, b1, bc);

    // layer 0
    hipLaunchKernelGGL((proj512_kernel<32>), dim3(M_ / 32), dim3(256), 0, stream,
                       x16, W0h, b0, xp);
    hipLaunchKernelGGL(lstm_rec_mfma, dim3(64), dim3(512), 0, stream, xp, Whh0h, h1);

    // layer 1
    hipLaunchKernelGGL((proj512_kernel<128>), dim3(M_ / 32), dim3(256), 0, stream,
                       h1, W1h, b1, xp);
    hipLaunchKernelGGL(lstm_rec_mfma, dim3(64), dim3(512), 0, stream, xp, Whh1h, h2);

    // head
    hipLaunchKernelGGL(head_kernel, dim3(M_ / 64), dim3(256), 0, stream,
                       h2, Wc16, bc, out);
}

// Round 7
// 500.568 us; speedup vs baseline: 3.8814x; 1.3625x over previous
//
#include <hip/hip_runtime.h>
#include <hip/hip_fp16.h>

#define B_ 256
#define T_ 512
#define H_ 128
#define M_ (B_ * T_)  // 131072 rows

typedef _Float16 f16x8 __attribute__((ext_vector_type(8)));
typedef float    f32x4 __attribute__((ext_vector_type(4)));

__device__ __forceinline__ float rcp_f(float a) { return __builtin_amdgcn_rcpf(a); }
__device__ __forceinline__ float sigmoid_f(float a) { return rcp_f(1.f + __expf(-a)); }
__device__ __forceinline__ float tanh_f(float a) { return 1.f - 2.f * rcp_f(__expf(2.f * a) + 1.f); }

// LDS-only barrier: global loads/stores stay in flight (T4: never vmcnt(0) per step).
__device__ __forceinline__ void lds_barrier() {
    asm volatile("s_waitcnt lgkmcnt(0)\n\ts_barrier" ::: "memory");
}

__device__ __forceinline__ __half cell_update(float g0, float g1, float g2, float g3, float& c) {
    float iv = sigmoid_f(g0), fv = sigmoid_f(g1);
    float gv = tanh_f(g2),   ov = sigmoid_f(g3);
    c = fv * c + iv * gv;
    return __float2half(ov * tanh_f(c));
}

// ---- device-visible (cross-XCD via L3) memory ops: sc0 sc1 ----
__device__ __forceinline__ void store_short_sc(uint64_t addr, unsigned v) {
    asm volatile("global_store_short %0, %1, off sc0 sc1" :: "v"(addr), "v"(v) : "memory");
}
__device__ __forceinline__ void store_flag_sc(uint64_t addr, unsigned v) {
    asm volatile("global_store_dword %0, %1, off sc0 sc1" :: "v"(addr), "v"(v) : "memory");
}
__device__ __forceinline__ unsigned load_flag_sc(uint64_t addr) {
    unsigned v;
    asm volatile("global_load_dword %0, %1, off sc0 sc1\n\ts_waitcnt vmcnt(0)"
                 : "=v"(v) : "v"(addr) : "memory");
    return v;
}
#define LOAD16_SC(dst, addr) \
    asm volatile("global_load_dwordx4 %0, %1, off sc0 sc1" : "=v"(dst) : "v"(addr) : "memory")

#define MFMA16(A, BV, C) __builtin_amdgcn_mfma_f32_16x16x32_f16((A), (BV), (C), 0, 0, 0)
#define MF4(AV, WARR, KT) \
    ac0 = MFMA16(AV, WARR[0][KT], ac0); \
    ac1 = MFMA16(AV, WARR[1][KT], ac1); \
    ac2 = MFMA16(AV, WARR[2][KT], ac2); \
    ac3 = MFMA16(AV, WARR[3][KT], ac3);

// ---------- one-time conversions ----------
__global__ __launch_bounds__(256)
void convert_kernel(const float* __restrict__ Wih0, const float* __restrict__ bih0, const float* __restrict__ bhh0,
                    const float* __restrict__ Whh0, const float* __restrict__ Wih1, const float* __restrict__ Whh1,
                    const float* __restrict__ bih1, const float* __restrict__ bhh1,
                    const float* __restrict__ Wl, const float* __restrict__ bl,
                    const float* __restrict__ Wo, const float* __restrict__ bo,
                    __half* __restrict__ W0b, __half* __restrict__ W1b,
                    __half* __restrict__ Whh0h, __half* __restrict__ Whh1h,
                    __half* __restrict__ Wc16, float* __restrict__ b0, float* __restrict__ b1,
                    float* __restrict__ bc)
{
    const int tid = threadIdx.x, bid = blockIdx.x;
    if (bid == 0) {
        for (int i = tid; i < 512; i += 256) { b0[i] = bih0[i] + bhh0[i]; b1[i] = bih1[i] + bhh1[i]; }
        for (int i = tid; i < 512 * 32; i += 256) {
            int r = i >> 5, k = i & 31;
            W0b[i] = __float2half(k < 30 ? Wih0[r * 30 + k] : 0.f);
        }
        for (int i = tid; i < 64 * 128; i += 256) {
            int j = i >> 7, k = i & 127;
            float a = 0.f;
            if (j < 63) for (int m = 0; m < 84; ++m) a += Wo[j * 84 + m] * Wl[m * 128 + k];
            Wc16[i] = __float2half(a);
        }
        if (tid < 64) {
            float a = 0.f;
            if (tid < 63) { a = bo[tid]; for (int m = 0; m < 84; ++m) a += Wo[tid * 84 + m] * bl[m]; }
            bc[tid] = a;
        }
    } else if (bid == 1) {
        for (int i = tid; i < 512 * 128; i += 256) W1b[i] = __float2half(Wih1[i]);
    } else if (bid == 2) {
        for (int i = tid; i < 512 * 128; i += 256) Whh0h[i] = __float2half(Whh0[i]);
    } else {
        for (int i = tid; i < 512 * 128; i += 256) Whh1h[i] = __float2half(Whh1[i]);
    }
}

// ---------- fused dual-layer recurrence: blocks 0-63 = layer0, 64-127 = layer1 ----------
__global__ __launch_bounds__(512, 1)
void lstm_fused(const float* __restrict__ x,
                const __half* __restrict__ W0b, const __half* __restrict__ Whh0h,
                const __half* __restrict__ W1b, const __half* __restrict__ Whh1h,
                const float* __restrict__ b0, const float* __restrict__ b1,
                __half* __restrict__ h1g, __half* __restrict__ h2g,
                unsigned* __restrict__ flags)
{
    const int bid = blockIdx.x;
    const bool producer = bid < 64;
    const int g = bid & 63;           // batch group: batches 4g..4g+3
    const int tid = threadIdx.x;
    const int w = tid >> 6;           // wave -> units 16w..16w+15
    const int lane = tid & 63;
    const int l15 = lane & 15, qg = lane >> 4;
    const int j = w * 16 + l15;       // this lane's unit
    const int r = l15 >> 2;           // A-row batch (duplicated 4x -> LDS broadcast)
    const bool act = (l15 & 3) == 0;  // lanes doing global h1 traffic

    // h tile: [4 batches][128 units] fp16, row stride 320B (2-way banks, conflict-free)
    __shared__ __align__(16) char hbuf_s[2][1280];
    __shared__ __align__(16) __half xl[4][128][32];  // producer x chunk (32KB)
    char* const hb0 = hbuf_s[0];
    char* const hb1 = hbuf_s[1];

    const int ro0 = r * 320 + 0 * 64 + qg * 16;
    const int ro1 = r * 320 + 1 * 64 + qg * 16;
    const int ro2 = r * 320 + 2 * 64 + qg * 16;
    const int ro3 = r * 320 + 3 * 64 + qg * 16;
    const int wo  = qg * 320 + j * 2;

    for (int i = tid; i < 320; i += 512) ((unsigned*)hb0)[i] = 0;  // h(-1) = 0

    float c = 0.f;
    float bias4[4];
    f16x8 wb[4][4];

    if (producer) {
        // Whh0 + Wih0 fragments, b0
        f16x8 wx[4];
#pragma unroll
        for (int q = 0; q < 4; ++q) {
            bias4[q] = b0[q * 128 + j];
            wx[q] = *reinterpret_cast<const f16x8*>(W0b + (size_t)(q * 128 + j) * 32 + qg * 8);
#pragma unroll
            for (int kt = 0; kt < 4; ++kt)
                wb[q][kt] = *reinterpret_cast<const f16x8*>(Whh0h + (size_t)(q * 128 + j) * 128 + kt * 32 + qg * 8);
        }
        // zero the x padding columns (30,31) once
        for (int idx = tid; idx < 1024; idx += 512) {
            int b4 = idx >> 8, rest = idx & 255;
            xl[b4][rest >> 1][30 + (rest & 1)] = __float2half(0.f);
        }
        const int b = g * 4 + qg;
        const uint64_t h1sb = (uint64_t)(uintptr_t)h1g + (((uint64_t)b * T_) * H_ + j) * 2;
        const uint64_t flagaddr = (uint64_t)(uintptr_t)(flags + (g * 8 + w));
        const char* xlb = (const char*)xl;
        const int xro = r * 8192 + qg * 16;
        __syncthreads();

#define PSTEP(TT, RB, WB) do {                                                  \
        const int ts_ = (TT);                                                   \
        const char* rp_ = (RB) ? hb1 : hb0;                                     \
        char* wp_ = (WB) ? hb1 : hb0;                                           \
        f16x8 a0_ = *(const f16x8*)(rp_ + ro0);                                 \
        f16x8 a1_ = *(const f16x8*)(rp_ + ro1);                                 \
        f16x8 a2_ = *(const f16x8*)(rp_ + ro2);                                 \
        f16x8 a3_ = *(const f16x8*)(rp_ + ro3);                                 \
        f16x8 ax_ = *(const f16x8*)(xlb + (xro + ts_ * 64));                    \
        f32x4 ac0 = (f32x4){bias4[0], 0.f, 0.f, 0.f};                           \
        f32x4 ac1 = (f32x4){bias4[1], 0.f, 0.f, 0.f};                           \
        f32x4 ac2 = (f32x4){bias4[2], 0.f, 0.f, 0.f};                           \
        f32x4 ac3 = (f32x4){bias4[3], 0.f, 0.f, 0.f};                           \
        ac0 = MFMA16(ax_, wx[0], ac0); ac1 = MFMA16(ax_, wx[1], ac1);           \
        ac2 = MFMA16(ax_, wx[2], ac2); ac3 = MFMA16(ax_, wx[3], ac3);           \
        MF4(a0_, wb, 0) MF4(a1_, wb, 1) MF4(a2_, wb, 2) MF4(a3_, wb, 3)         \
        __half hh_ = cell_update(ac0[0], ac1[0], ac2[0], ac3[0], c);            \
        *(__half*)(wp_ + wo) = hh_;                                             \
        { unsigned hv_ = (unsigned)__builtin_bit_cast(unsigned short, hh_);     \
          store_short_sc(h1sb + (uint64_t)(cbase + ts_) * 256, hv_); }          \
        if (((cbase + ts_) & 7) == 7) {                                         \
            asm volatile("s_waitcnt vmcnt(0)" ::: "memory");                    \
            if (lane == 0) store_flag_sc(flagaddr, (unsigned)(cbase + ts_ + 1)); \
        }                                                                       \
        lds_barrier();                                                          \
    } while (0)

        for (int chunk = 0; chunk < 4; ++chunk) {
            const int cbase = chunk << 7;
            // stage x chunk: 4 batches x 128 steps x 30 f32 -> fp16 LDS
#pragma unroll 1
            for (int b4 = 0; b4 < 4; ++b4) {
                const float* src = x + ((size_t)(g * 4 + b4) * T_ + cbase) * 30;
                for (int idx = tid; idx < 3840; idx += 512) {
                    int tt = idx / 30, ii = idx - tt * 30;
                    xl[b4][tt][ii] = __float2half(src[idx]);
                }
            }
            __syncthreads();
            for (int ts = 0; ts < 128; ts += 2) {
                PSTEP(ts, 0, 1);
                PSTEP(ts + 1, 1, 0);
            }
        }
    } else {
        // consumer: Whh1 + Wih1 fragments, b1
        f16x8 wi[4][4];
#pragma unroll
        for (int q = 0; q < 4; ++q) {
            bias4[q] = b1[q * 128 + j];
#pragma unroll
            for (int kt = 0; kt < 4; ++kt) {
                wb[q][kt] = *reinterpret_cast<const f16x8*>(Whh1h + (size_t)(q * 128 + j) * 128 + kt * 32 + qg * 8);
                wi[q][kt] = *reinterpret_cast<const f16x8*>(W1b   + (size_t)(q * 128 + j) * 128 + kt * 32 + qg * 8);
            }
        }
        const uint64_t h1cb = (uint64_t)(uintptr_t)h1g + (((uint64_t)(g * 4 + r) * T_) * H_ + qg * 8) * 2;
        const uint64_t flagbase = (uint64_t)(uintptr_t)(flags + g * 8);
        __half* h2p = h2g + ((size_t)(g * 4 + qg) * T_) * H_ + j;
        uint4 haA0 = {0,0,0,0}, haA1 = {0,0,0,0}, haA2 = {0,0,0,0}, haA3 = {0,0,0,0};
        uint4 haB0 = {0,0,0,0}, haB1 = {0,0,0,0}, haB2 = {0,0,0,0}, haB3 = {0,0,0,0};
        __syncthreads();

#define CSTEP(KK, HC0, HC1, HC2, HC3, HN0, HN1, HN2, HN3, ISSUE) do {           \
        const int t_ = tg + (KK);                                               \
        const char* rp_ = ((KK) & 1) ? hb1 : hb0;                               \
        char* wp_ = ((KK) & 1) ? hb0 : hb1;                                     \
        f16x8 a0_ = *(const f16x8*)(rp_ + ro0);                                 \
        f16x8 a1_ = *(const f16x8*)(rp_ + ro1);                                 \
        f16x8 a2_ = *(const f16x8*)(rp_ + ro2);                                 \
        f16x8 a3_ = *(const f16x8*)(rp_ + ro3);                                 \
        f32x4 ac0 = (f32x4){bias4[0], 0.f, 0.f, 0.f};                           \
        f32x4 ac1 = (f32x4){bias4[1], 0.f, 0.f, 0.f};                           \
        f32x4 ac2 = (f32x4){bias4[2], 0.f, 0.f, 0.f};                           \
        f32x4 ac3 = (f32x4){bias4[3], 0.f, 0.f, 0.f};                           \
        MF4(a0_, wb, 0) MF4(a1_, wb, 1) MF4(a2_, wb, 2) MF4(a3_, wb, 3)         \
        asm volatile("s_waitcnt vmcnt(0)" ::: "memory");                        \
        __builtin_amdgcn_sched_barrier(0);                                      \
        { f16x8 hf0_ = __builtin_bit_cast(f16x8, HC0);                          \
          f16x8 hf1_ = __builtin_bit_cast(f16x8, HC1);                          \
          f16x8 hf2_ = __builtin_bit_cast(f16x8, HC2);                          \
          f16x8 hf3_ = __builtin_bit_cast(f16x8, HC3);                          \
          MF4(hf0_, wi, 0) MF4(hf1_, wi, 1) MF4(hf2_, wi, 2) MF4(hf3_, wi, 3) } \
        if (ISSUE) { if (act) {                                                 \
            uint64_t ba_ = h1cb + (uint64_t)(t_ + 1) * 256;                     \
            LOAD16_SC(HN0, ba_);       LOAD16_SC(HN1, ba_ + 64);                \
            LOAD16_SC(HN2, ba_ + 128); LOAD16_SC(HN3, ba_ + 192); } }           \
        __half hh_ = cell_update(ac0[0], ac1[0], ac2[0], ac3[0], c);            \
        *(__half*)(wp_ + wo) = hh_;                                             \
        h2p[(size_t)t_ * H_] = hh_;                                             \
        lds_barrier();                                                          \
    } while (0)

        for (int tg = 0; tg < T_; tg += 8) {
            // wait until producer published steps tg..tg+7 (flag >= tg+8 on all 8 waves)
            const unsigned target = (unsigned)(tg + 8);
            for (;;) {
                unsigned v = 0xFFFFFFFFu;
                if (lane < 8) v = load_flag_sc(flagbase + (uint64_t)lane * 4);
                v = min(v, (unsigned)__shfl_xor((int)v, 1));
                v = min(v, (unsigned)__shfl_xor((int)v, 2));
                v = min(v, (unsigned)__shfl_xor((int)v, 4));
                unsigned seen = (unsigned)__shfl((int)v, 0);
                if (seen >= target) break;
                __builtin_amdgcn_s_sleep(4);
            }
            if (act) {  // first h1 tile of the group
                uint64_t ba = h1cb + (uint64_t)tg * 256;
                LOAD16_SC(haA0, ba);       LOAD16_SC(haA1, ba + 64);
                LOAD16_SC(haA2, ba + 128); LOAD16_SC(haA3, ba + 192);
            }
            CSTEP(0, haA0, haA1, haA2, haA3, haB0, haB1, haB2, haB3, 1);
            CSTEP(1, haB0, haB1, haB2, haB3, haA0, haA1, haA2, haA3, 1);
            CSTEP(2, haA0, haA1, haA2, haA3, haB0, haB1, haB2, haB3, 1);
            CSTEP(3, haB0, haB1, haB2, haB3, haA0, haA1, haA2, haA3, 1);
            CSTEP(4, haA0, haA1, haA2, haA3, haB0, haB1, haB2, haB3, 1);
            CSTEP(5, haB0, haB1, haB2, haB3, haA0, haA1, haA2, haA3, 1);
            CSTEP(6, haA0, haA1, haA2, haA3, haB0, haB1, haB2, haB3, 1);
            CSTEP(7, haB0, haB1, haB2, haB3, haA0, haA1, haA2, haA3, 0);
        }
    }
}

// ---------- head: out = h2 @ Wc^T + bc (63 cols, f32) ----------
__global__ __launch_bounds__(256, 4)
void head_kernel(const __half* __restrict__ in, const __half* __restrict__ W16,
                 const float* __restrict__ bias, float* __restrict__ outp)
{
    constexpr int KK = 128;
    const int lane = threadIdx.x & 63;
    const int wn = threadIdx.x >> 6;
    const int rowbase = blockIdx.x * 64;  // ROWT=4
    const int colbase = wn * 16;
    const int l15 = lane & 15, lk = (lane >> 4) * 8;

    float bcol = bias[colbase + l15];
    f32x4 acc[4];
#pragma unroll
    for (int rt = 0; rt < 4; ++rt) acc[rt] = (f32x4){0.f, 0.f, 0.f, 0.f};

#pragma unroll
    for (int kt = 0; kt < 4; ++kt) {
        f16x8 bv = *reinterpret_cast<const f16x8*>(W16 + (size_t)(colbase + l15) * KK + kt * 32 + lk);
#pragma unroll
        for (int rt = 0; rt < 4; ++rt) {
            f16x8 a = *reinterpret_cast<const f16x8*>(in + (size_t)(rowbase + rt * 16 + l15) * KK + kt * 32 + lk);
            acc[rt] = __builtin_amdgcn_mfma_f32_16x16x32_f16(a, bv, acc[rt], 0, 0, 0);
        }
    }
    const int col = colbase + l15;
#pragma unroll
    for (int rt = 0; rt < 4; ++rt)
#pragma unroll
        for (int rr = 0; rr < 4; ++rr) {
            const int row = rowbase + rt * 16 + (lane >> 4) * 4 + rr;
            if (col < 63) outp[(size_t)row * 63 + col] = acc[rt][rr] + bcol;
        }
}

extern "C" void kernel_launch(void* const* d_in, const int* in_sizes, int n_in,
                              void* d_out, int out_size, void* d_ws, size_t ws_size,
                              hipStream_t stream)
{
    const float* x    = (const float*)d_in[0];
    const float* Wih0 = (const float*)d_in[1];
    const float* Whh0 = (const float*)d_in[2];
    const float* bih0 = (const float*)d_in[3];
    const float* bhh0 = (const float*)d_in[4];
    const float* Wih1 = (const float*)d_in[5];
    const float* Whh1 = (const float*)d_in[6];
    const float* bih1 = (const float*)d_in[7];
    const float* bhh1 = (const float*)d_in[8];
    const float* Wl   = (const float*)d_in[9];
    const float* bl   = (const float*)d_in[10];
    const float* Wo   = (const float*)d_in[11];
    const float* bo   = (const float*)d_in[12];
    float* out = (float*)d_out;

    char* ws = (char*)d_ws;
    size_t off = 0;
    auto carve = [&](size_t bytes) { void* p = ws + off; off += (bytes + 255) & ~(size_t)255; return p; };
    __half* h1    = (__half*)carve((size_t)M_ * 128 * 2);  // 33.5 MB
    __half* h2    = (__half*)carve((size_t)M_ * 128 * 2);  // 33.5 MB
    __half* W0b   = (__half*)carve(512 * 32 * 2);
    __half* W1b   = (__half*)carve(512 * 128 * 2);
    __half* Whh0h = (__half*)carve(512 * 128 * 2);
    __half* Whh1h = (__half*)carve(512 * 128 * 2);
    __half* Wc16  = (__half*)carve(64 * 128 * 2);
    float*  b0    = (float*)carve(512 * 4);
    float*  b1    = (float*)carve(512 * 4);
    float*  bc    = (float*)carve(64 * 4);
    unsigned* flags = (unsigned*)carve(64 * 8 * 4);

    hipLaunchKernelGGL(convert_kernel, dim3(4), dim3(256), 0, stream,
                       Wih0, bih0, bhh0, Whh0, Wih1, Whh1, bih1, bhh1, Wl, bl, Wo, bo,
                       W0b, W1b, Whh0h, Whh1h, Wc16, b0, b1, bc);

    hipMemsetAsync(flags, 0, 64 * 8 * 4, stream);  // handshake flags must start at 0 every replay

    hipLaunchKernelGGL(lstm_fused, dim3(128), dim3(512), 0, stream,
                       x, W0b, Whh0h, W1b, Whh1h, b0, b1, h1, h2, flags);

    hipLaunchKernelGGL(head_kernel, dim3(M_ / 64), dim3(256), 0, stream,
                       h2, Wc16, bc, out);
}